// Round 11
// baseline (231.205 us; speedup 1.0000x reference)
//
#include <hip/hip_runtime.h>

typedef float f32x4 __attribute__((ext_vector_type(4)));
typedef float f32x16 __attribute__((ext_vector_type(16)));
typedef short s16x8 __attribute__((ext_vector_type(8)));
typedef unsigned short u16;
typedef unsigned long long u64;

#define BN 4
#define CC 256
#define NN 4096

static __device__ __forceinline__ u16 f2bf(float x) {
    unsigned int u = __float_as_uint(x);
    u += 0x7FFF + ((u >> 16) & 1);   // round-to-nearest-even
    return (u16)(u >> 16);
}

// ---------------------------------------------------------------------------
// Kernel 0: transpose weights.
// wT[src][c][0..7]=qw[r][c], [8..15]=kw[r][c]; wvT[a][cp][c] = wv_a[c][cp]
// ---------------------------------------------------------------------------
__global__ __launch_bounds__(256) void k_wtrans(
    const float* __restrict__ qLw, const float* __restrict__ kLw,
    const float* __restrict__ qUw, const float* __restrict__ kUw,
    const float* __restrict__ vUw, const float* __restrict__ vLw,
    float* __restrict__ wT, float* __restrict__ wvT)
{
    int a = blockIdx.x, t = threadIdx.x;
    const float* qw = a ? qUw : qLw;
    const float* kw = a ? kUw : kLw;
#pragma unroll
    for (int r = 0; r < 8; ++r) {
        wT[((size_t)a * 256 + t) * 16 + r]     = qw[r * 256 + t];
        wT[((size_t)a * 256 + t) * 16 + 8 + r] = kw[r * 256 + t];
    }
    const float* wv = a ? vLw : vUw;
    for (int cp = 0; cp < 64; ++cp)
        wvT[((size_t)a * 64 + cp) * 256 + t] = wv[(size_t)t * 64 + cp];
}

// ---------------------------------------------------------------------------
// Kernel 1: Q/K projections -> bf16. qbf/kbf: [attend][n][8] bf16.
// 512 thr = 4 c-quarters; Q pre-scaled by log2(e).
// ---------------------------------------------------------------------------
__global__ __launch_bounds__(512) void k_qkprep(
    const float* __restrict__ fL, const float* __restrict__ fU,
    const float* __restrict__ wT,
    const float* __restrict__ qLb, const float* __restrict__ kLb,
    const float* __restrict__ qUb, const float* __restrict__ kUb,
    u16* __restrict__ qbf, u16* __restrict__ kbf)
{
    int blk = blockIdx.x;
    int nc = blk & 31, b = (blk >> 5) & 3, src = blk >> 7;
    const float* f = src ? fU : fL;
    int qa = src, ka = 1 - src;
    int t = threadIdx.x;
    int nl = t & 127;
    int cs = __builtin_amdgcn_readfirstlane(t >> 7) * 64;   // 0,64,128,192
    int n = nc * 128 + nl;
    const float* fp = f + (size_t)b * 256 * NN + n;
    const float* wbase = wT + (size_t)src * 4096;

    float acc[16];
#pragma unroll
    for (int r = 0; r < 16; ++r) acc[r] = 0.f;

#pragma unroll 4
    for (int c = cs; c < cs + 64; ++c) {
        float fv = fp[(size_t)c * NN];
        const float* wr = wbase + (size_t)c * 16;   // uniform -> s_load
#pragma unroll
        for (int r = 0; r < 16; ++r) acc[r] += wr[r] * fv;
    }

    __shared__ float red[4][128][17];
    int cc = t >> 7;
#pragma unroll
    for (int r = 0; r < 16; ++r) red[cc][nl][r] = acc[r];
    __syncthreads();

    if (t < 128) {
        const float* bq = src ? qUb : qLb;
        const float* bk = src ? kUb : kLb;
        const float L2E = 1.4426950408889634f;
        int nn = nc * 128 + t;
        u16 pq[8], pk[8];
#pragma unroll
        for (int r = 0; r < 8; ++r) {
            float sq = red[0][t][r] + red[1][t][r] + red[2][t][r] + red[3][t][r];
            float sk = red[0][t][8+r] + red[1][t][8+r] + red[2][t][8+r] + red[3][t][8+r];
            pq[r] = f2bf((sq + bq[r]) * L2E);
            pk[r] = f2bf( sk + bk[r]);
        }
        uint4 vq, vk;
        vq.x = pq[0] | ((unsigned)pq[1] << 16); vq.y = pq[2] | ((unsigned)pq[3] << 16);
        vq.z = pq[4] | ((unsigned)pq[5] << 16); vq.w = pq[6] | ((unsigned)pq[7] << 16);
        vk.x = pk[0] | ((unsigned)pk[1] << 16); vk.y = pk[2] | ((unsigned)pk[3] << 16);
        vk.z = pk[4] | ((unsigned)pk[5] << 16); vk.w = pk[6] | ((unsigned)pk[7] << 16);
        *(uint4*)(qbf + (((size_t)qa * BN + b) * NN + nn) * 8) = vq;
        *(uint4*)(kbf + (((size_t)ka * BN + b) * NN + nn) * 8) = vk;
    }
}

// ---------------------------------------------------------------------------
// Kernel 2: Z[ab][m] = sum_n exp2(q'[m].k[n]) via 32x32x16 MFMA.
// ---------------------------------------------------------------------------
__global__ __launch_bounds__(256) void k_zsum(
    const u16* __restrict__ qbf, const u16* __restrict__ kbf,
    float* __restrict__ Z)
{
    int blk = blockIdx.x;
    int mt = blk & 31, ab = blk >> 5;
    int t = threadIdx.x, l = t & 63;
    int w = __builtin_amdgcn_readfirstlane(t >> 6);
    int l31 = l & 31, g2 = l >> 5;
    int m0 = mt * 128 + w * 32;

    const u16* qab = qbf + (size_t)ab * NN * 8;
    const u16* kab = kbf + (size_t)ab * NN * 8;

    s16x8 af = *(const s16x8*)(qab + (size_t)(m0 + l31) * 8);
    if (g2) af = (s16x8)0;

    auto ldb = [&](int i) -> s16x8 {
        s16x8 r = *(const s16x8*)(kab + (size_t)(i * 32 + l31) * 8);
        return g2 ? (s16x8)0 : r;
    };

    float zp[16];
#pragma unroll
    for (int r = 0; r < 16; ++r) zp[r] = 0.f;

    s16x8 b0 = ldb(0), b1 = ldb(1);
#pragma unroll 1
    for (int i = 0; i < 128; ++i) {
        int nx = i + 2 < 127 ? i + 2 : 127;
        s16x8 bn = ldb(nx);
        f32x16 s = __builtin_amdgcn_mfma_f32_32x32x16_bf16(af, b0, (f32x16)0.f, 0, 0, 0);
#pragma unroll
        for (int r = 0; r < 16; ++r) zp[r] += __builtin_exp2f(s[r]);
        b0 = b1; b1 = bn;
    }

#pragma unroll
    for (int r = 0; r < 16; ++r) {
        float v = zp[r];
#pragma unroll
        for (int d = 1; d < 32; d <<= 1) v += __shfl_xor(v, d, 64);
        zp[r] = v;
    }
    if (l31 == 0) {
#pragma unroll
        for (int r = 0; r < 16; ++r) {
            int m = m0 + (r & 3) + 8 * (r >> 2) + 4 * g2;
            Z[(size_t)ab * NN + m] = zp[r];
        }
    }
}

// ---------------------------------------------------------------------------
// Kernel 3: vp tiled: vpt[ab][kstep(128)][c(256)][mi(32)] bf16
// value = (grouped_conv + bias) / Z[m]
// ---------------------------------------------------------------------------
__global__ __launch_bounds__(256) void k_vprep(
    const float* __restrict__ fL, const float* __restrict__ fU,
    const float* __restrict__ wvT,
    const float* __restrict__ vUb, const float* __restrict__ vLb,
    const float* __restrict__ Z, u16* __restrict__ vpt)
{
    int blk = blockIdx.x;
    int mc = blk & 31, g = (blk >> 5) & 3, ab = blk >> 7;
    int a = ab >> 2, b = ab & 3;
    const float* f    = a ? fL : fU;
    const float* bias = a ? vLb : vUb;
    int t = threadIdx.x, l = t & 63;
    int wu = __builtin_amdgcn_readfirstlane(t >> 6);
    int m0 = mc * 128 + l * 2;

    const float* fg = f + ((size_t)b * 256 + g * 64) * NN + m0;
    const float* wq = wvT + (size_t)a * 16384 + g * 64 + wu * 16;

    float acc[16][2];
#pragma unroll
    for (int j = 0; j < 16; ++j) { acc[j][0] = 0.f; acc[j][1] = 0.f; }

    for (int cp = 0; cp < 64; ++cp) {
        float2 fv = *(const float2*)(fg + (size_t)cp * NN);
        const float* wr = wq + (size_t)cp * 256;   // wave-uniform -> s_load
        float4 w0 = *(const float4*)(wr);
        float4 w1 = *(const float4*)(wr + 4);
        float4 w2 = *(const float4*)(wr + 8);
        float4 w3 = *(const float4*)(wr + 12);
        float wv[16] = {w0.x,w0.y,w0.z,w0.w, w1.x,w1.y,w1.z,w1.w,
                        w2.x,w2.y,w2.z,w2.w, w3.x,w3.y,w3.z,w3.w};
#pragma unroll
        for (int j = 0; j < 16; ++j) {
            acc[j][0] += wv[j] * fv.x;
            acc[j][1] += wv[j] * fv.y;
        }
    }

    float2 z = *(const float2*)(Z + (size_t)ab * NN + m0);
    float zr0 = 1.f / z.x, zr1 = 1.f / z.y;
    int mt = m0 >> 5, mi = m0 & 31;
    u16* vpo = vpt + (((size_t)ab * 128 + mt) * 256 + g * 64 + wu * 16) * 32 + mi;
#pragma unroll
    for (int j = 0; j < 16; ++j) {
        float bj = bias[g * 64 + wu * 16 + j];
        unsigned pk = (unsigned)f2bf((acc[j][0] + bj) * zr0) |
                      ((unsigned)f2bf((acc[j][1] + bj) * zr1) << 16);
        *(unsigned*)(vpo + (size_t)j * 32) = pk;
    }
}

// ---------------------------------------------------------------------------
// Kernel 4: out = base + beta * (vp . exp2(q'^T k))
// grid 512 = ab(8) x nt(64); 512 thr = 8 waves; block 256c x 64n.
// PV on 32x32x16 MFMA: wave = 64c strip (cs=w>>1) x 32n half (nh=w&1);
// egen on 16x16x32: wave role (ng=w&3, mh=w>>2).
// 128-m windows (32 of them), 4x32m tiles pipelined inside; relaxed barrier
// (lgkmcnt drain only -- global prefetches fly across); ping-pong A regs with
// incrementing pointer + imm offsets; rolling q prefetch; 16-slot XOR swizzle.
// FIX vs R10: q stride jump at kt==2 (load runs one piece ahead); A-pointer
// increment clamped at ti<126 (no read past vpt end).
// ---------------------------------------------------------------------------
__global__ __launch_bounds__(512, 4) void k_main(
    const float* __restrict__ fL, const float* __restrict__ fU,
    const u16* __restrict__ qbf, const u16* __restrict__ kbf,
    const u16* __restrict__ vpt, const float* __restrict__ beta_p,
    float* __restrict__ out)
{
    int blk = blockIdx.x;
    int ab = blk & 7, nt = blk >> 3;
    int a = ab >> 2, b = ab & 3;
    int n0 = nt * 64;
    int t = threadIdx.x, l = t & 63;
    int w = __builtin_amdgcn_readfirstlane(t >> 6);   // 0..7
    int c15 = l & 15, g = l >> 4;     // 16x16 roles (egen)
    int l31 = l & 31, g2 = l >> 5;    // 32x32 roles (PV)
    int cs = w >> 1, nh = w & 1;      // PV: 64c strip, 32n half
    int ng = w & 3, mh = w >> 2;      // egen: 16n group, 64m half
    int swz = c15 << 4;               // (row&15)<<4 for both write & read rows

    __shared__ u16 ebuf[2][64][128];  // 32 KB; row = n (256 B), col = m
    char* eb = (char*)ebuf;
    int rrow = (nh * 32 + l31) << 8;  // read row byte base
    int wrow = (ng * 16 + c15) << 8;  // write row byte base

    const u16* qab = qbf + (size_t)ab * NN * 8;
    const u16* kab = kbf + (size_t)ab * NN * 8;

    // egen B-frag (constant): k-col n = n0 + ng*16 + c15 (k = 8g+e, g>0 pad)
    s16x8 bkf = *(const s16x8*)(kab + (size_t)(n0 + ng * 16 + c15) * 8);
    if (g) bkf = (s16x8)0;

    f32x16 acc0 = (f32x16)0.f, acc1 = (f32x16)0.f;

    // egen one 16m x 16n piece (piece kt of a window) into buffer ebw
    auto epiece = [&](char* ebw, int kt, s16x8 qv) {
        f32x4 s = __builtin_amdgcn_mfma_f32_16x16x32_bf16(qv, bkf, (f32x4)0.f, 0, 0, 0);
        float e0 = __builtin_exp2f(s[0]);
        float e1 = __builtin_exp2f(s[1]);
        float e2 = __builtin_exp2f(s[2]);
        float e3 = __builtin_exp2f(s[3]);
        unsigned lo, hi;
        asm("v_cvt_pk_bf16_f32 %0, %1, %2" : "=v"(lo) : "v"(e0), "v"(e1));
        asm("v_cvt_pk_bf16_f32 %0, %1, %2" : "=v"(hi) : "v"(e2), "v"(e3));
        uint2 pk; pk.x = lo; pk.y = hi;
        *(uint2*)(ebw + wrow + ((mh * 128 + kt * 32 + g * 8) ^ swz)) = pk;
    };

    // ---- prologue: window 0 E -> ebuf[0]
    {
        const u16* qp = qab + (size_t)(mh * 64 + c15) * 8;
#pragma unroll
        for (int kt = 0; kt < 4; ++kt) {
            s16x8 qv = *(const s16x8*)(qp + (size_t)kt * 128);
            if (g) qv = (s16x8)0;
            epiece(eb, kt, qv);
        }
    }

    // A pointer: per-lane; preload tile0, then points at next tile
    const u16* apt = vpt + (size_t)ab * (128ull * 8192)
                   + (size_t)(cs * 64 + l31) * 32 + g2 * 8;
    s16x8 aA[4], aB[4];
    aA[0] = *(const s16x8*)(apt);
    aA[1] = *(const s16x8*)(apt + 16);
    aA[2] = *(const s16x8*)(apt + 1024);
    aA[3] = *(const s16x8*)(apt + 1040);
    apt += 8192;

    // rolling q: qA = piece (win1, kt0)
    const u16* qpt = qab + (size_t)(128 + mh * 64 + c15) * 8;
    s16x8 qA = *(const s16x8*)(qpt);
    if (g) qA = (s16x8)0;
    s16x8 qB = (s16x8)0;
    qpt += 128;   // -> piece (win1, kt1)

    __syncthreads();

    // one 32-m tile: consume Sin + qcur, prefetch Sout + qstore
    auto ktbody = [&](s16x8 (&Sin)[4], s16x8 (&Sout)[4],
                      s16x8& qcur, s16x8& qstore,
                      int kt, int ti, bool doeg, char* ebr, char* ebw) {
        // A prefetch for tile ti+1 (stays in flight across relaxed barrier)
        Sout[0] = *(const s16x8*)(apt);
        Sout[1] = *(const s16x8*)(apt + 16);
        Sout[2] = *(const s16x8*)(apt + 1024);
        Sout[3] = *(const s16x8*)(apt + 1040);
        apt += (ti < 126) ? 8192 : 0;   // FIX: never step past last tile
        // q prefetch (next egen piece); the load runs one piece AHEAD of kt,
        // so the window-boundary jump (+80 rows) applies after loading kt3,
        // i.e. in the kt==2 body.  FIX vs R10 (was kt==3).
        s16x8 qnew = *(const s16x8*)(qpt);
        qpt += (kt == 2) ? 640 : 128;
        // B-frags (LDS, swizzled)
        s16x8 bf0 = *(const s16x8*)(ebr + rrow + ((kt * 64 +  0 + g2 * 16) ^ swz));
        s16x8 bf1 = *(const s16x8*)(ebr + rrow + ((kt * 64 + 32 + g2 * 16) ^ swz));
        // egen piece kt for next window (overlaps load latency)
        if (doeg) epiece(ebw, kt, qcur);
        if (g) qnew = (s16x8)0;
        qstore = qnew;
        // PV: 4 x 32x32x16
        __builtin_amdgcn_s_setprio(1);
        acc0 = __builtin_amdgcn_mfma_f32_32x32x16_bf16(Sin[0], bf0, acc0, 0, 0, 0);
        acc1 = __builtin_amdgcn_mfma_f32_32x32x16_bf16(Sin[2], bf0, acc1, 0, 0, 0);
        acc0 = __builtin_amdgcn_mfma_f32_32x32x16_bf16(Sin[1], bf1, acc0, 0, 0, 0);
        acc1 = __builtin_amdgcn_mfma_f32_32x32x16_bf16(Sin[3], bf1, acc1, 0, 0, 0);
        __builtin_amdgcn_s_setprio(0);
    };

#pragma unroll 1
    for (int k = 0; k < 32; ++k) {
        char* ebr = eb + ((k & 1) << 14);
        char* ebw = eb + (((k & 1) ^ 1) << 14);
        bool doeg = (k < 31);
        int kb = k * 4;
        ktbody(aA, aB, qA, qB, 0, kb + 0, doeg, ebr, ebw);
        ktbody(aB, aA, qB, qA, 1, kb + 1, doeg, ebr, ebw);
        ktbody(aA, aB, qA, qB, 2, kb + 2, doeg, ebr, ebw);
        ktbody(aB, aA, qB, qA, 3, kb + 3, doeg, ebr, ebw);
        // relaxed barrier: drain LDS only; global prefetches stay in flight
        asm volatile("s_waitcnt lgkmcnt(0)\n\ts_barrier" ::: "memory");
    }

    // ---- epilogue: out = base + beta*acc  (32x32 C/D layout)
    float beta = beta_p[0];
    const float* base = a ? fU : fL;
    float* op = out + (size_t)a * ((size_t)BN * CC * NN);
    int nidx = n0 + nh * 32 + l31;
#pragma unroll
    for (int r = 0; r < 16; ++r) {
        int co = (r & 3) + 8 * (r >> 2) + 4 * g2;
        size_t i0 = ((size_t)b * CC + cs * 64 + co) * NN + nidx;
        op[i0] = base[i0] + beta * acc0[r];
        size_t i1 = i0 + (size_t)32 * NN;
        op[i1] = base[i1] + beta * acc1[r];
    }
}

// ---------------------------------------------------------------------------
extern "C" void kernel_launch(void* const* d_in, const int* in_sizes, int n_in,
                              void* d_out, int out_size, void* d_ws, size_t ws_size,
                              hipStream_t stream) {
    const float* fL  = (const float*)d_in[0];
    const float* fU  = (const float*)d_in[1];
    const float* qLw = (const float*)d_in[2];
    const float* qLb = (const float*)d_in[3];
    const float* kUw = (const float*)d_in[4];
    const float* kUb = (const float*)d_in[5];
    const float* vUw = (const float*)d_in[6];
    const float* vUb = (const float*)d_in[7];
    const float* qUw = (const float*)d_in[8];
    const float* qUb = (const float*)d_in[9];
    const float* kLw = (const float*)d_in[10];
    const float* kLb = (const float*)d_in[11];
    const float* vLw = (const float*)d_in[12];
    const float* vLb = (const float*)d_in[13];
    const float* beta = (const float*)d_in[14];

    char* ws = (char*)d_ws;
    float* wT  = (float*)(ws);                 // [0, 32768)
    float* wvT = (float*)(ws + 32768);         // [32768, 163840)
    u16*   qbf = (u16*)  (ws + 163840);        // [163840, 688128)
    u16*   kbf = (u16*)  (ws + 688128);        // [688128, 1212416)
    float* Z   = (float*)(ws + 1212416);       // [1212416, 1343488)
    u16*   vpt = (u16*)  (ws + 1343488);       // [1343488, +16 MB)
    float* out = (float*)d_out;

    k_wtrans<<<2, 256, 0, stream>>>(qLw, kLw, qUw, kUw, vUw, vLw, wT, wvT);
    k_qkprep<<<256, 512, 0, stream>>>(fL, fU, wT, qLb, kLb, qUb, kUb, qbf, kbf);
    k_zsum<<<256, 256, 0, stream>>>(qbf, kbf, Z);
    k_vprep<<<1024, 256, 0, stream>>>(fL, fU, wvT, vUb, vLb, Z, vpt);
    k_main<<<512, 512, 0, stream>>>(fL, fU, qbf, kbf, vpt, beta, out);
}

// Round 12
// 176.806 us; speedup vs baseline: 1.3077x; 1.3077x over previous
//
#include <hip/hip_runtime.h>

typedef float f32x4 __attribute__((ext_vector_type(4)));
typedef float f32x16 __attribute__((ext_vector_type(16)));
typedef short s16x8 __attribute__((ext_vector_type(8)));
typedef unsigned short u16;
typedef unsigned long long u64;

#define BN 4
#define CC 256
#define NN 4096

static __device__ __forceinline__ u16 f2bf(float x) {
    unsigned int u = __float_as_uint(x);
    u += 0x7FFF + ((u >> 16) & 1);   // round-to-nearest-even
    return (u16)(u >> 16);
}

// ---------------------------------------------------------------------------
// Kernel 0: transpose weights.
// wT[src][c][0..7]=qw[r][c], [8..15]=kw[r][c]; wvT[a][cp][c] = wv_a[c][cp]
// ---------------------------------------------------------------------------
__global__ __launch_bounds__(256) void k_wtrans(
    const float* __restrict__ qLw, const float* __restrict__ kLw,
    const float* __restrict__ qUw, const float* __restrict__ kUw,
    const float* __restrict__ vUw, const float* __restrict__ vLw,
    float* __restrict__ wT, float* __restrict__ wvT)
{
    int a = blockIdx.x, t = threadIdx.x;
    const float* qw = a ? qUw : qLw;
    const float* kw = a ? kUw : kLw;
#pragma unroll
    for (int r = 0; r < 8; ++r) {
        wT[((size_t)a * 256 + t) * 16 + r]     = qw[r * 256 + t];
        wT[((size_t)a * 256 + t) * 16 + 8 + r] = kw[r * 256 + t];
    }
    const float* wv = a ? vLw : vUw;
    for (int cp = 0; cp < 64; ++cp)
        wvT[((size_t)a * 64 + cp) * 256 + t] = wv[(size_t)t * 64 + cp];
}

// ---------------------------------------------------------------------------
// Kernel 1: Q/K projections -> bf16. qbf/kbf: [attend][n][8] bf16.
// 512 thr = 4 c-quarters; Q pre-scaled by log2(e).
// ---------------------------------------------------------------------------
__global__ __launch_bounds__(512) void k_qkprep(
    const float* __restrict__ fL, const float* __restrict__ fU,
    const float* __restrict__ wT,
    const float* __restrict__ qLb, const float* __restrict__ kLb,
    const float* __restrict__ qUb, const float* __restrict__ kUb,
    u16* __restrict__ qbf, u16* __restrict__ kbf)
{
    int blk = blockIdx.x;
    int nc = blk & 31, b = (blk >> 5) & 3, src = blk >> 7;
    const float* f = src ? fU : fL;
    int qa = src, ka = 1 - src;
    int t = threadIdx.x;
    int nl = t & 127;
    int cs = __builtin_amdgcn_readfirstlane(t >> 7) * 64;   // 0,64,128,192
    int n = nc * 128 + nl;
    const float* fp = f + (size_t)b * 256 * NN + n;
    const float* wbase = wT + (size_t)src * 4096;

    float acc[16];
#pragma unroll
    for (int r = 0; r < 16; ++r) acc[r] = 0.f;

#pragma unroll 4
    for (int c = cs; c < cs + 64; ++c) {
        float fv = fp[(size_t)c * NN];
        const float* wr = wbase + (size_t)c * 16;   // uniform -> s_load
#pragma unroll
        for (int r = 0; r < 16; ++r) acc[r] += wr[r] * fv;
    }

    __shared__ float red[4][128][17];
    int cc = t >> 7;
#pragma unroll
    for (int r = 0; r < 16; ++r) red[cc][nl][r] = acc[r];
    __syncthreads();

    if (t < 128) {
        const float* bq = src ? qUb : qLb;
        const float* bk = src ? kUb : kLb;
        const float L2E = 1.4426950408889634f;
        int nn = nc * 128 + t;
        u16 pq[8], pk[8];
#pragma unroll
        for (int r = 0; r < 8; ++r) {
            float sq = red[0][t][r] + red[1][t][r] + red[2][t][r] + red[3][t][r];
            float sk = red[0][t][8+r] + red[1][t][8+r] + red[2][t][8+r] + red[3][t][8+r];
            pq[r] = f2bf((sq + bq[r]) * L2E);
            pk[r] = f2bf( sk + bk[r]);
        }
        uint4 vq, vk;
        vq.x = pq[0] | ((unsigned)pq[1] << 16); vq.y = pq[2] | ((unsigned)pq[3] << 16);
        vq.z = pq[4] | ((unsigned)pq[5] << 16); vq.w = pq[6] | ((unsigned)pq[7] << 16);
        vk.x = pk[0] | ((unsigned)pk[1] << 16); vk.y = pk[2] | ((unsigned)pk[3] << 16);
        vk.z = pk[4] | ((unsigned)pk[5] << 16); vk.w = pk[6] | ((unsigned)pk[7] << 16);
        *(uint4*)(qbf + (((size_t)qa * BN + b) * NN + nn) * 8) = vq;
        *(uint4*)(kbf + (((size_t)ka * BN + b) * NN + nn) * 8) = vk;
    }
}

// ---------------------------------------------------------------------------
// Kernel 2: Z[ab][m] = sum_n exp2(q'[m].k[n]) via 32x32x16 MFMA.
// ---------------------------------------------------------------------------
__global__ __launch_bounds__(256) void k_zsum(
    const u16* __restrict__ qbf, const u16* __restrict__ kbf,
    float* __restrict__ Z)
{
    int blk = blockIdx.x;
    int mt = blk & 31, ab = blk >> 5;
    int t = threadIdx.x, l = t & 63;
    int w = __builtin_amdgcn_readfirstlane(t >> 6);
    int l31 = l & 31, g2 = l >> 5;
    int m0 = mt * 128 + w * 32;

    const u16* qab = qbf + (size_t)ab * NN * 8;
    const u16* kab = kbf + (size_t)ab * NN * 8;

    s16x8 af = *(const s16x8*)(qab + (size_t)(m0 + l31) * 8);
    if (g2) af = (s16x8)0;

    auto ldb = [&](int i) -> s16x8 {
        s16x8 r = *(const s16x8*)(kab + (size_t)(i * 32 + l31) * 8);
        return g2 ? (s16x8)0 : r;
    };

    float zp[16];
#pragma unroll
    for (int r = 0; r < 16; ++r) zp[r] = 0.f;

    s16x8 b0 = ldb(0), b1 = ldb(1);
#pragma unroll 1
    for (int i = 0; i < 128; ++i) {
        int nx = i + 2 < 127 ? i + 2 : 127;
        s16x8 bn = ldb(nx);
        f32x16 s = __builtin_amdgcn_mfma_f32_32x32x16_bf16(af, b0, (f32x16)0.f, 0, 0, 0);
#pragma unroll
        for (int r = 0; r < 16; ++r) zp[r] += __builtin_exp2f(s[r]);
        b0 = b1; b1 = bn;
    }

#pragma unroll
    for (int r = 0; r < 16; ++r) {
        float v = zp[r];
#pragma unroll
        for (int d = 1; d < 32; d <<= 1) v += __shfl_xor(v, d, 64);
        zp[r] = v;
    }
    if (l31 == 0) {
#pragma unroll
        for (int r = 0; r < 16; ++r) {
            int m = m0 + (r & 3) + 8 * (r >> 2) + 4 * g2;
            Z[(size_t)ab * NN + m] = zp[r];
        }
    }
}

// ---------------------------------------------------------------------------
// Kernel 3: vp tiled: vpt[ab][kstep(128)][c(256)][mi(32)] bf16
// value = (grouped_conv + bias) / Z[m]
// ---------------------------------------------------------------------------
__global__ __launch_bounds__(256) void k_vprep(
    const float* __restrict__ fL, const float* __restrict__ fU,
    const float* __restrict__ wvT,
    const float* __restrict__ vUb, const float* __restrict__ vLb,
    const float* __restrict__ Z, u16* __restrict__ vpt)
{
    int blk = blockIdx.x;
    int mc = blk & 31, g = (blk >> 5) & 3, ab = blk >> 7;
    int a = ab >> 2, b = ab & 3;
    const float* f    = a ? fL : fU;
    const float* bias = a ? vLb : vUb;
    int t = threadIdx.x, l = t & 63;
    int wu = __builtin_amdgcn_readfirstlane(t >> 6);
    int m0 = mc * 128 + l * 2;

    const float* fg = f + ((size_t)b * 256 + g * 64) * NN + m0;
    const float* wq = wvT + (size_t)a * 16384 + g * 64 + wu * 16;

    float acc[16][2];
#pragma unroll
    for (int j = 0; j < 16; ++j) { acc[j][0] = 0.f; acc[j][1] = 0.f; }

    for (int cp = 0; cp < 64; ++cp) {
        float2 fv = *(const float2*)(fg + (size_t)cp * NN);
        const float* wr = wq + (size_t)cp * 256;   // wave-uniform -> s_load
        float4 w0 = *(const float4*)(wr);
        float4 w1 = *(const float4*)(wr + 4);
        float4 w2 = *(const float4*)(wr + 8);
        float4 w3 = *(const float4*)(wr + 12);
        float wv[16] = {w0.x,w0.y,w0.z,w0.w, w1.x,w1.y,w1.z,w1.w,
                        w2.x,w2.y,w2.z,w2.w, w3.x,w3.y,w3.z,w3.w};
#pragma unroll
        for (int j = 0; j < 16; ++j) {
            acc[j][0] += wv[j] * fv.x;
            acc[j][1] += wv[j] * fv.y;
        }
    }

    float2 z = *(const float2*)(Z + (size_t)ab * NN + m0);
    float zr0 = 1.f / z.x, zr1 = 1.f / z.y;
    int mt = m0 >> 5, mi = m0 & 31;
    u16* vpo = vpt + (((size_t)ab * 128 + mt) * 256 + g * 64 + wu * 16) * 32 + mi;
#pragma unroll
    for (int j = 0; j < 16; ++j) {
        float bj = bias[g * 64 + wu * 16 + j];
        unsigned pk = (unsigned)f2bf((acc[j][0] + bj) * zr0) |
                      ((unsigned)f2bf((acc[j][1] + bj) * zr1) << 16);
        *(unsigned*)(vpo + (size_t)j * 32) = pk;
    }
}

// ---------------------------------------------------------------------------
// Kernel 4: out = base + beta * (vp . exp2(q'^T k)), E-gen on MFMA.
// == R9 structure (best measured) with ONE change: the per-window barrier is
// relaxed to {s_waitcnt lgkmcnt(0); s_barrier} so global A/q prefetches stay
// in flight across the barrier (T4 counted-vmcnt effect) instead of being
// drained by __syncthreads' implicit vmcnt(0).
// grid 512 = ab(8) x nt(64); 512 thr = 8 waves; block tile 256c x 64n.
// ---------------------------------------------------------------------------
__global__ __launch_bounds__(512, 4) void k_main(
    const float* __restrict__ fL, const float* __restrict__ fU,
    const u16* __restrict__ qbf, const u16* __restrict__ kbf,
    const u16* __restrict__ vpt, const float* __restrict__ beta_p,
    float* __restrict__ out)
{
    int blk = blockIdx.x;
    int ab = blk & 7, nt = blk >> 3;
    int a = ab >> 2, b = ab & 3;
    int n0 = nt * 64;
    int t = threadIdx.x, l = t & 63;
    int w = __builtin_amdgcn_readfirstlane(t >> 6);   // 0..7
    int c15 = l & 15, g = l >> 4;
    int ng = w & 3;            // egen n-group
    int mh = w >> 2;           // egen m-half
    int swz = (c15 & 7) << 4;

    __shared__ u16 ebuf[2][64][64];   // 16 KB, rows 128 B, XOR-swizzled

    auto eptr = [&](int p, int n, int mbyte) -> char* {
        return ((char*)ebuf) + (p << 13) + (n << 7) + (mbyte ^ swz);
    };

    const u16* qab = qbf + (size_t)ab * NN * 8;
    const u16* kab = kbf + (size_t)ab * NN * 8;

    // egen B-frag (constant): k-col n = n0 + ng*16 + c15 (k = 8g+e, g>0 pad)
    s16x8 bkf = *(const s16x8*)(kab + (size_t)(n0 + ng * 16 + c15) * 8);
    if (g) bkf = (s16x8)0;

    // PV A lane base: wave's 32-c strip within a 32m k-tile
    const u16* apb = vpt + (size_t)ab * (128ull * 8192)
                   + (size_t)(w * 32 + c15) * 32 + g * 8;

    f32x4 acc[2][4];   // [cf][nf]
#pragma unroll
    for (int i = 0; i < 2; ++i)
#pragma unroll
        for (int j = 0; j < 4; ++j) acc[i][j] = (f32x4)0.f;

    // q rows for this wave's egen share: m = win*64 + (mh*2+mq2)*16 + c15
    auto qld = [&](int win, int mq2) -> s16x8 {
        s16x8 r = *(const s16x8*)(qab + (size_t)(win * 64 + (mh * 2 + mq2) * 16 + c15) * 8);
        return g ? (s16x8)0 : r;
    };

    // egen this wave's share of window -> buffer pbuf
    auto egen = [&](int pbuf, const s16x8& q0, const s16x8& q1) {
#pragma unroll
        for (int mq2 = 0; mq2 < 2; ++mq2) {
            f32x4 s = __builtin_amdgcn_mfma_f32_16x16x32_bf16(
                mq2 ? q1 : q0, bkf, (f32x4)0.f, 0, 0, 0);
            float e0 = __builtin_exp2f(s[0]);
            float e1 = __builtin_exp2f(s[1]);
            float e2 = __builtin_exp2f(s[2]);
            float e3 = __builtin_exp2f(s[3]);
            unsigned lo, hi;
            asm("v_cvt_pk_bf16_f32 %0, %1, %2" : "=v"(lo) : "v"(e0), "v"(e1));
            asm("v_cvt_pk_bf16_f32 %0, %1, %2" : "=v"(hi) : "v"(e2), "v"(e3));
            uint2 pk; pk.x = lo; pk.y = hi;
            *(uint2*)eptr(pbuf, ng * 16 + c15, (mh * 2 + mq2) * 32 + g * 8) = pk;
        }
    };

    // one window step: PV on buffer P (window kwin) with A-regs aC;
    // prefetch A(kwin+1)->aN, q(kwin+2)->qN; egen window kwin+1 using qC.
    auto step = [&](int P, int kwin,
                    s16x8 (&aC)[2][2], s16x8 (&aN)[2][2],
                    s16x8 (&qC)[2], s16x8 (&qN)[2], bool doeg) {
        // A prefetch (longest latency, issue first)
        int kn = kwin + 1 < 63 ? kwin + 1 : 63;
        const u16* apn = apb + (size_t)(2 * kn) * 8192;
#pragma unroll
        for (int cf = 0; cf < 2; ++cf) {
            aN[cf][0] = *(const s16x8*)(apn + cf * 512);
            aN[cf][1] = *(const s16x8*)(apn + 8192 + cf * 512);
        }
        // q prefetch (early: latency spans the whole step)
        int kq = kwin + 2 < 63 ? kwin + 2 : 63;
        qN[0] = qld(kq, 0);
        qN[1] = qld(kq, 1);

        // B-frags kc=0 (LDS)
        s16x8 bf[4];
#pragma unroll
        for (int nf = 0; nf < 4; ++nf)
            bf[nf] = *(const s16x8*)eptr(P, nf * 16 + c15, g * 16);
        // E(next window) -> other buffer (VALU/trans, overlaps MFMA)
        if (doeg) egen(P ^ 1, qC[0], qC[1]);
        // PV kc=0
        __builtin_amdgcn_s_setprio(1);
#pragma unroll
        for (int cf = 0; cf < 2; ++cf)
#pragma unroll
            for (int nf = 0; nf < 4; ++nf)
                acc[cf][nf] = __builtin_amdgcn_mfma_f32_16x16x32_bf16(
                    aC[cf][0], bf[nf], acc[cf][nf], 0, 0, 0);
        __builtin_amdgcn_s_setprio(0);
        // B-frags kc=1 + PV kc=1
#pragma unroll
        for (int nf = 0; nf < 4; ++nf)
            bf[nf] = *(const s16x8*)eptr(P, nf * 16 + c15, 64 + g * 16);
        __builtin_amdgcn_s_setprio(1);
#pragma unroll
        for (int cf = 0; cf < 2; ++cf)
#pragma unroll
            for (int nf = 0; nf < 4; ++nf)
                acc[cf][nf] = __builtin_amdgcn_mfma_f32_16x16x32_bf16(
                    aC[cf][1], bf[nf], acc[cf][nf], 0, 0, 0);
        __builtin_amdgcn_s_setprio(0);
        // relaxed barrier: drain own LDS ops only; global prefetches (aN, qN)
        // stay in flight across the barrier (compiler waits vmcnt(N) at use).
        asm volatile("s_waitcnt lgkmcnt(0)\n\ts_barrier" ::: "memory");
    };

    // ---- prologue: E(0) -> ebuf[0]; q(1) -> qA; A(0) -> afA
    {
        s16x8 z0 = qld(0, 0), z1 = qld(0, 1);
        egen(0, z0, z1);
    }
    s16x8 qA[2], qB[2];
    qA[0] = qld(1, 0); qA[1] = qld(1, 1);
    s16x8 afA[2][2], afB[2][2];
#pragma unroll
    for (int cf = 0; cf < 2; ++cf) {
        afA[cf][0] = *(const s16x8*)(apb + cf * 512);
        afA[cf][1] = *(const s16x8*)(apb + 8192 + cf * 512);
    }
    __syncthreads();

#pragma unroll 1
    for (int k2 = 0; k2 < 32; ++k2) {
        step(0, 2 * k2,     afA, afB, qA, qB, true);
        step(1, 2 * k2 + 1, afB, afA, qB, qA, k2 < 31);
    }

    // ---- epilogue: out = base + beta*acc
    float beta = beta_p[0];
    const float* base = a ? fU : fL;
    float* op = out + (size_t)a * ((size_t)BN * CC * NN);
#pragma unroll
    for (int cf = 0; cf < 2; ++cf)
#pragma unroll
        for (int nf = 0; nf < 4; ++nf)
#pragma unroll
            for (int r = 0; r < 4; ++r) {
                int c = w * 32 + cf * 16 + g * 4 + r;
                int n = n0 + nf * 16 + c15;
                size_t idx = ((size_t)b * CC + c) * NN + n;
                op[idx] = base[idx] + beta * acc[cf][nf][r];
            }
}

// ---------------------------------------------------------------------------
extern "C" void kernel_launch(void* const* d_in, const int* in_sizes, int n_in,
                              void* d_out, int out_size, void* d_ws, size_t ws_size,
                              hipStream_t stream) {
    const float* fL  = (const float*)d_in[0];
    const float* fU  = (const float*)d_in[1];
    const float* qLw = (const float*)d_in[2];
    const float* qLb = (const float*)d_in[3];
    const float* kUw = (const float*)d_in[4];
    const float* kUb = (const float*)d_in[5];
    const float* vUw = (const float*)d_in[6];
    const float* vUb = (const float*)d_in[7];
    const float* qUw = (const float*)d_in[8];
    const float* qUb = (const float*)d_in[9];
    const float* kLw = (const float*)d_in[10];
    const float* kLb = (const float*)d_in[11];
    const float* vLw = (const float*)d_in[12];
    const float* vLb = (const float*)d_in[13];
    const float* beta = (const float*)d_in[14];

    char* ws = (char*)d_ws;
    float* wT  = (float*)(ws);                 // [0, 32768)
    float* wvT = (float*)(ws + 32768);         // [32768, 163840)
    u16*   qbf = (u16*)  (ws + 163840);        // [163840, 688128)
    u16*   kbf = (u16*)  (ws + 688128);        // [688128, 1212416)
    float* Z   = (float*)(ws + 1212416);       // [1212416, 1343488)
    u16*   vpt = (u16*)  (ws + 1343488);       // [1343488, +16 MB)
    float* out = (float*)d_out;

    k_wtrans<<<2, 256, 0, stream>>>(qLw, kLw, qUw, kUw, vUw, vLw, wT, wvT);
    k_qkprep<<<256, 512, 0, stream>>>(fL, fU, wT, qLb, kLb, qUb, kUb, qbf, kbf);
    k_zsum<<<256, 256, 0, stream>>>(qbf, kbf, Z);
    k_vprep<<<1024, 256, 0, stream>>>(fL, fU, wvT, vUb, vLb, Z, vpt);
    k_main<<<512, 512, 0, stream>>>(fL, fU, qbf, kbf, vpt, beta, out);
}

// Round 13
// 176.422 us; speedup vs baseline: 1.3105x; 1.0022x over previous
//
#include <hip/hip_runtime.h>

typedef float f32x4 __attribute__((ext_vector_type(4)));
typedef float f32x16 __attribute__((ext_vector_type(16)));
typedef short s16x8 __attribute__((ext_vector_type(8)));
typedef unsigned short u16;
typedef unsigned long long u64;

#define BN 4
#define CC 256
#define NN 4096

static __device__ __forceinline__ u16 f2bf(float x) {
    unsigned int u = __float_as_uint(x);
    u += 0x7FFF + ((u >> 16) & 1);   // round-to-nearest-even
    return (u16)(u >> 16);
}

// ---------------------------------------------------------------------------
// Kernel 0: transpose weights.
// wT[src][c][0..7]=qw[r][c], [8..15]=kw[r][c]; wvT[a][cp][c] = wv_a[c][cp]
// ---------------------------------------------------------------------------
__global__ __launch_bounds__(256) void k_wtrans(
    const float* __restrict__ qLw, const float* __restrict__ kLw,
    const float* __restrict__ qUw, const float* __restrict__ kUw,
    const float* __restrict__ vUw, const float* __restrict__ vLw,
    float* __restrict__ wT, float* __restrict__ wvT)
{
    int a = blockIdx.x, t = threadIdx.x;
    const float* qw = a ? qUw : qLw;
    const float* kw = a ? kUw : kLw;
#pragma unroll
    for (int r = 0; r < 8; ++r) {
        wT[((size_t)a * 256 + t) * 16 + r]     = qw[r * 256 + t];
        wT[((size_t)a * 256 + t) * 16 + 8 + r] = kw[r * 256 + t];
    }
    const float* wv = a ? vLw : vUw;
    for (int cp = 0; cp < 64; ++cp)
        wvT[((size_t)a * 64 + cp) * 256 + t] = wv[(size_t)t * 64 + cp];
}

// ---------------------------------------------------------------------------
// Kernel 1: Q/K projections -> bf16. qbf/kbf: [attend][n][8] bf16.
// 512 thr = 4 c-quarters; Q pre-scaled by log2(e).
// ---------------------------------------------------------------------------
__global__ __launch_bounds__(512) void k_qkprep(
    const float* __restrict__ fL, const float* __restrict__ fU,
    const float* __restrict__ wT,
    const float* __restrict__ qLb, const float* __restrict__ kLb,
    const float* __restrict__ qUb, const float* __restrict__ kUb,
    u16* __restrict__ qbf, u16* __restrict__ kbf)
{
    int blk = blockIdx.x;
    int nc = blk & 31, b = (blk >> 5) & 3, src = blk >> 7;
    const float* f = src ? fU : fL;
    int qa = src, ka = 1 - src;
    int t = threadIdx.x;
    int nl = t & 127;
    int cs = __builtin_amdgcn_readfirstlane(t >> 7) * 64;   // 0,64,128,192
    int n = nc * 128 + nl;
    const float* fp = f + (size_t)b * 256 * NN + n;
    const float* wbase = wT + (size_t)src * 4096;

    float acc[16];
#pragma unroll
    for (int r = 0; r < 16; ++r) acc[r] = 0.f;

#pragma unroll 4
    for (int c = cs; c < cs + 64; ++c) {
        float fv = fp[(size_t)c * NN];
        const float* wr = wbase + (size_t)c * 16;   // uniform -> s_load
#pragma unroll
        for (int r = 0; r < 16; ++r) acc[r] += wr[r] * fv;
    }

    __shared__ float red[4][128][17];
    int cc = t >> 7;
#pragma unroll
    for (int r = 0; r < 16; ++r) red[cc][nl][r] = acc[r];
    __syncthreads();

    if (t < 128) {
        const float* bq = src ? qUb : qLb;
        const float* bk = src ? kUb : kLb;
        const float L2E = 1.4426950408889634f;
        int nn = nc * 128 + t;
        u16 pq[8], pk[8];
#pragma unroll
        for (int r = 0; r < 8; ++r) {
            float sq = red[0][t][r] + red[1][t][r] + red[2][t][r] + red[3][t][r];
            float sk = red[0][t][8+r] + red[1][t][8+r] + red[2][t][8+r] + red[3][t][8+r];
            pq[r] = f2bf((sq + bq[r]) * L2E);
            pk[r] = f2bf( sk + bk[r]);
        }
        uint4 vq, vk;
        vq.x = pq[0] | ((unsigned)pq[1] << 16); vq.y = pq[2] | ((unsigned)pq[3] << 16);
        vq.z = pq[4] | ((unsigned)pq[5] << 16); vq.w = pq[6] | ((unsigned)pq[7] << 16);
        vk.x = pk[0] | ((unsigned)pk[1] << 16); vk.y = pk[2] | ((unsigned)pk[3] << 16);
        vk.z = pk[4] | ((unsigned)pk[5] << 16); vk.w = pk[6] | ((unsigned)pk[7] << 16);
        *(uint4*)(qbf + (((size_t)qa * BN + b) * NN + nn) * 8) = vq;
        *(uint4*)(kbf + (((size_t)ka * BN + b) * NN + nn) * 8) = vk;
    }
}

// ---------------------------------------------------------------------------
// Kernel 2: Z[ab][m] = sum_n exp2(q'[m].k[n]) via 32x32x16 MFMA.
// ---------------------------------------------------------------------------
__global__ __launch_bounds__(256) void k_zsum(
    const u16* __restrict__ qbf, const u16* __restrict__ kbf,
    float* __restrict__ Z)
{
    int blk = blockIdx.x;
    int mt = blk & 31, ab = blk >> 5;
    int t = threadIdx.x, l = t & 63;
    int w = __builtin_amdgcn_readfirstlane(t >> 6);
    int l31 = l & 31, g2 = l >> 5;
    int m0 = mt * 128 + w * 32;

    const u16* qab = qbf + (size_t)ab * NN * 8;
    const u16* kab = kbf + (size_t)ab * NN * 8;

    s16x8 af = *(const s16x8*)(qab + (size_t)(m0 + l31) * 8);
    if (g2) af = (s16x8)0;

    auto ldb = [&](int i) -> s16x8 {
        s16x8 r = *(const s16x8*)(kab + (size_t)(i * 32 + l31) * 8);
        return g2 ? (s16x8)0 : r;
    };

    float zp[16];
#pragma unroll
    for (int r = 0; r < 16; ++r) zp[r] = 0.f;

    s16x8 b0 = ldb(0), b1 = ldb(1);
#pragma unroll 1
    for (int i = 0; i < 128; ++i) {
        int nx = i + 2 < 127 ? i + 2 : 127;
        s16x8 bn = ldb(nx);
        f32x16 s = __builtin_amdgcn_mfma_f32_32x32x16_bf16(af, b0, (f32x16)0.f, 0, 0, 0);
#pragma unroll
        for (int r = 0; r < 16; ++r) zp[r] += __builtin_exp2f(s[r]);
        b0 = b1; b1 = bn;
    }

#pragma unroll
    for (int r = 0; r < 16; ++r) {
        float v = zp[r];
#pragma unroll
        for (int d = 1; d < 32; d <<= 1) v += __shfl_xor(v, d, 64);
        zp[r] = v;
    }
    if (l31 == 0) {
#pragma unroll
        for (int r = 0; r < 16; ++r) {
            int m = m0 + (r & 3) + 8 * (r >> 2) + 4 * g2;
            Z[(size_t)ab * NN + m] = zp[r];
        }
    }
}

// ---------------------------------------------------------------------------
// Kernel 3: vp tiled: vpt[ab][kstep(128)][c(256)][mi(32)] bf16
// value = (grouped_conv + bias) / Z[m]
// ---------------------------------------------------------------------------
__global__ __launch_bounds__(256) void k_vprep(
    const float* __restrict__ fL, const float* __restrict__ fU,
    const float* __restrict__ wvT,
    const float* __restrict__ vUb, const float* __restrict__ vLb,
    const float* __restrict__ Z, u16* __restrict__ vpt)
{
    int blk = blockIdx.x;
    int mc = blk & 31, g = (blk >> 5) & 3, ab = blk >> 7;
    int a = ab >> 2, b = ab & 3;
    const float* f    = a ? fL : fU;
    const float* bias = a ? vLb : vUb;
    int t = threadIdx.x, l = t & 63;
    int wu = __builtin_amdgcn_readfirstlane(t >> 6);
    int m0 = mc * 128 + l * 2;

    const float* fg = f + ((size_t)b * 256 + g * 64) * NN + m0;
    const float* wq = wvT + (size_t)a * 16384 + g * 64 + wu * 16;

    float acc[16][2];
#pragma unroll
    for (int j = 0; j < 16; ++j) { acc[j][0] = 0.f; acc[j][1] = 0.f; }

    for (int cp = 0; cp < 64; ++cp) {
        float2 fv = *(const float2*)(fg + (size_t)cp * NN);
        const float* wr = wq + (size_t)cp * 256;   // wave-uniform -> s_load
        float4 w0 = *(const float4*)(wr);
        float4 w1 = *(const float4*)(wr + 4);
        float4 w2 = *(const float4*)(wr + 8);
        float4 w3 = *(const float4*)(wr + 12);
        float wv[16] = {w0.x,w0.y,w0.z,w0.w, w1.x,w1.y,w1.z,w1.w,
                        w2.x,w2.y,w2.z,w2.w, w3.x,w3.y,w3.z,w3.w};
#pragma unroll
        for (int j = 0; j < 16; ++j) {
            acc[j][0] += wv[j] * fv.x;
            acc[j][1] += wv[j] * fv.y;
        }
    }

    float2 z = *(const float2*)(Z + (size_t)ab * NN + m0);
    float zr0 = 1.f / z.x, zr1 = 1.f / z.y;
    int mt = m0 >> 5, mi = m0 & 31;
    u16* vpo = vpt + (((size_t)ab * 128 + mt) * 256 + g * 64 + wu * 16) * 32 + mi;
#pragma unroll
    for (int j = 0; j < 16; ++j) {
        float bj = bias[g * 64 + wu * 16 + j];
        unsigned pk = (unsigned)f2bf((acc[j][0] + bj) * zr0) |
                      ((unsigned)f2bf((acc[j][1] + bj) * zr1) << 16);
        *(unsigned*)(vpo + (size_t)j * 32) = pk;
    }
}

// ---------------------------------------------------------------------------
// Kernel 4: out = base + beta * (vp . exp2(q'^T k)), E-gen on MFMA.
// == R9 structure (best measured) with ONE change: the per-window barrier is
// relaxed to {s_waitcnt lgkmcnt(0); s_barrier} so global A/q prefetches stay
// in flight across the barrier (T4 counted-vmcnt effect) instead of being
// drained by __syncthreads' implicit vmcnt(0).
// grid 512 = ab(8) x nt(64); 512 thr = 8 waves; block tile 256c x 64n.
// ---------------------------------------------------------------------------
__global__ __launch_bounds__(512, 4) void k_main(
    const float* __restrict__ fL, const float* __restrict__ fU,
    const u16* __restrict__ qbf, const u16* __restrict__ kbf,
    const u16* __restrict__ vpt, const float* __restrict__ beta_p,
    float* __restrict__ out)
{
    int blk = blockIdx.x;
    int ab = blk & 7, nt = blk >> 3;
    int a = ab >> 2, b = ab & 3;
    int n0 = nt * 64;
    int t = threadIdx.x, l = t & 63;
    int w = __builtin_amdgcn_readfirstlane(t >> 6);   // 0..7
    int c15 = l & 15, g = l >> 4;
    int ng = w & 3;            // egen n-group
    int mh = w >> 2;           // egen m-half
    int swz = (c15 & 7) << 4;

    __shared__ u16 ebuf[2][64][64];   // 16 KB, rows 128 B, XOR-swizzled

    auto eptr = [&](int p, int n, int mbyte) -> char* {
        return ((char*)ebuf) + (p << 13) + (n << 7) + (mbyte ^ swz);
    };

    const u16* qab = qbf + (size_t)ab * NN * 8;
    const u16* kab = kbf + (size_t)ab * NN * 8;

    // egen B-frag (constant): k-col n = n0 + ng*16 + c15 (k = 8g+e, g>0 pad)
    s16x8 bkf = *(const s16x8*)(kab + (size_t)(n0 + ng * 16 + c15) * 8);
    if (g) bkf = (s16x8)0;

    // PV A lane base: wave's 32-c strip within a 32m k-tile
    const u16* apb = vpt + (size_t)ab * (128ull * 8192)
                   + (size_t)(w * 32 + c15) * 32 + g * 8;

    f32x4 acc[2][4];   // [cf][nf]
#pragma unroll
    for (int i = 0; i < 2; ++i)
#pragma unroll
        for (int j = 0; j < 4; ++j) acc[i][j] = (f32x4)0.f;

    // q rows for this wave's egen share: m = win*64 + (mh*2+mq2)*16 + c15
    auto qld = [&](int win, int mq2) -> s16x8 {
        s16x8 r = *(const s16x8*)(qab + (size_t)(win * 64 + (mh * 2 + mq2) * 16 + c15) * 8);
        return g ? (s16x8)0 : r;
    };

    // egen this wave's share of window -> buffer pbuf
    auto egen = [&](int pbuf, const s16x8& q0, const s16x8& q1) {
#pragma unroll
        for (int mq2 = 0; mq2 < 2; ++mq2) {
            f32x4 s = __builtin_amdgcn_mfma_f32_16x16x32_bf16(
                mq2 ? q1 : q0, bkf, (f32x4)0.f, 0, 0, 0);
            float e0 = __builtin_exp2f(s[0]);
            float e1 = __builtin_exp2f(s[1]);
            float e2 = __builtin_exp2f(s[2]);
            float e3 = __builtin_exp2f(s[3]);
            unsigned lo, hi;
            asm("v_cvt_pk_bf16_f32 %0, %1, %2" : "=v"(lo) : "v"(e0), "v"(e1));
            asm("v_cvt_pk_bf16_f32 %0, %1, %2" : "=v"(hi) : "v"(e2), "v"(e3));
            uint2 pk; pk.x = lo; pk.y = hi;
            *(uint2*)eptr(pbuf, ng * 16 + c15, (mh * 2 + mq2) * 32 + g * 8) = pk;
        }
    };

    // one window step: PV on buffer P (window kwin) with A-regs aC;
    // prefetch A(kwin+1)->aN, q(kwin+2)->qN; egen window kwin+1 using qC.
    auto step = [&](int P, int kwin,
                    s16x8 (&aC)[2][2], s16x8 (&aN)[2][2],
                    s16x8 (&qC)[2], s16x8 (&qN)[2], bool doeg) {
        // A prefetch (longest latency, issue first)
        int kn = kwin + 1 < 63 ? kwin + 1 : 63;
        const u16* apn = apb + (size_t)(2 * kn) * 8192;
#pragma unroll
        for (int cf = 0; cf < 2; ++cf) {
            aN[cf][0] = *(const s16x8*)(apn + cf * 512);
            aN[cf][1] = *(const s16x8*)(apn + 8192 + cf * 512);
        }
        // q prefetch (early: latency spans the whole step)
        int kq = kwin + 2 < 63 ? kwin + 2 : 63;
        qN[0] = qld(kq, 0);
        qN[1] = qld(kq, 1);

        // B-frags kc=0 (LDS)
        s16x8 bf[4];
#pragma unroll
        for (int nf = 0; nf < 4; ++nf)
            bf[nf] = *(const s16x8*)eptr(P, nf * 16 + c15, g * 16);
        // E(next window) -> other buffer (VALU/trans, overlaps MFMA)
        if (doeg) egen(P ^ 1, qC[0], qC[1]);
        // PV kc=0
        __builtin_amdgcn_s_setprio(1);
#pragma unroll
        for (int cf = 0; cf < 2; ++cf)
#pragma unroll
            for (int nf = 0; nf < 4; ++nf)
                acc[cf][nf] = __builtin_amdgcn_mfma_f32_16x16x32_bf16(
                    aC[cf][0], bf[nf], acc[cf][nf], 0, 0, 0);
        __builtin_amdgcn_s_setprio(0);
        // B-frags kc=1 + PV kc=1
#pragma unroll
        for (int nf = 0; nf < 4; ++nf)
            bf[nf] = *(const s16x8*)eptr(P, nf * 16 + c15, 64 + g * 16);
        __builtin_amdgcn_s_setprio(1);
#pragma unroll
        for (int cf = 0; cf < 2; ++cf)
#pragma unroll
            for (int nf = 0; nf < 4; ++nf)
                acc[cf][nf] = __builtin_amdgcn_mfma_f32_16x16x32_bf16(
                    aC[cf][1], bf[nf], acc[cf][nf], 0, 0, 0);
        __builtin_amdgcn_s_setprio(0);
        // relaxed barrier: drain own LDS ops only; global prefetches (aN, qN)
        // stay in flight across the barrier (compiler waits vmcnt(N) at use).
        asm volatile("s_waitcnt lgkmcnt(0)\n\ts_barrier" ::: "memory");
    };

    // ---- prologue: E(0) -> ebuf[0]; q(1) -> qA; A(0) -> afA
    {
        s16x8 z0 = qld(0, 0), z1 = qld(0, 1);
        egen(0, z0, z1);
    }
    s16x8 qA[2], qB[2];
    qA[0] = qld(1, 0); qA[1] = qld(1, 1);
    s16x8 afA[2][2], afB[2][2];
#pragma unroll
    for (int cf = 0; cf < 2; ++cf) {
        afA[cf][0] = *(const s16x8*)(apb + cf * 512);
        afA[cf][1] = *(const s16x8*)(apb + 8192 + cf * 512);
    }
    __syncthreads();

#pragma unroll 1
    for (int k2 = 0; k2 < 32; ++k2) {
        step(0, 2 * k2,     afA, afB, qA, qB, true);
        step(1, 2 * k2 + 1, afB, afA, qB, qA, k2 < 31);
    }

    // ---- epilogue: out = base + beta*acc
    float beta = beta_p[0];
    const float* base = a ? fU : fL;
    float* op = out + (size_t)a * ((size_t)BN * CC * NN);
#pragma unroll
    for (int cf = 0; cf < 2; ++cf)
#pragma unroll
        for (int nf = 0; nf < 4; ++nf)
#pragma unroll
            for (int r = 0; r < 4; ++r) {
                int c = w * 32 + cf * 16 + g * 4 + r;
                int n = n0 + nf * 16 + c15;
                size_t idx = ((size_t)b * CC + c) * NN + n;
                op[idx] = base[idx] + beta * acc[cf][nf][r];
            }
}

// ---------------------------------------------------------------------------
extern "C" void kernel_launch(void* const* d_in, const int* in_sizes, int n_in,
                              void* d_out, int out_size, void* d_ws, size_t ws_size,
                              hipStream_t stream) {
    const float* fL  = (const float*)d_in[0];
    const float* fU  = (const float*)d_in[1];
    const float* qLw = (const float*)d_in[2];
    const float* qLb = (const float*)d_in[3];
    const float* kUw = (const float*)d_in[4];
    const float* kUb = (const float*)d_in[5];
    const float* vUw = (const float*)d_in[6];
    const float* vUb = (const float*)d_in[7];
    const float* qUw = (const float*)d_in[8];
    const float* qUb = (const float*)d_in[9];
    const float* kLw = (const float*)d_in[10];
    const float* kLb = (const float*)d_in[11];
    const float* vLw = (const float*)d_in[12];
    const float* vLb = (const float*)d_in[13];
    const float* beta = (const float*)d_in[14];

    char* ws = (char*)d_ws;
    float* wT  = (float*)(ws);                 // [0, 32768)
    float* wvT = (float*)(ws + 32768);         // [32768, 163840)
    u16*   qbf = (u16*)  (ws + 163840);        // [163840, 688128)
    u16*   kbf = (u16*)  (ws + 688128);        // [688128, 1212416)
    float* Z   = (float*)(ws + 1212416);       // [1212416, 1343488)
    u16*   vpt = (u16*)  (ws + 1343488);       // [1343488, +16 MB)
    float* out = (float*)d_out;

    k_wtrans<<<2, 256, 0, stream>>>(qLw, kLw, qUw, kUw, vUw, vLw, wT, wvT);
    k_qkprep<<<256, 512, 0, stream>>>(fL, fU, wT, qLb, kLb, qUb, kUb, qbf, kbf);
    k_zsum<<<256, 256, 0, stream>>>(qbf, kbf, Z);
    k_vprep<<<1024, 256, 0, stream>>>(fL, fU, wvT, vUb, vLb, Z, vpt);
    k_main<<<512, 512, 0, stream>>>(fL, fU, qbf, kbf, vpt, beta, out);
}